// Round 1
// baseline (154.531 us; speedup 1.0000x reference)
//
#include <hip/hip_runtime.h>
#include <math.h>

// Problem constants (fixed by setup_inputs)
constexpr int N_ = 512;
constexpr int L_ = 65536;

// ws layout (floats):
//   terms: [0, 8192)            512 * 12 floats: {Lr,Li, t0r,t0i, t1r,t1i, t2r,t2i, t3r,t3i, pad,pad}
//   XT:    [8192, 8192+131072)  65536 float2, transposed atRoots: XT[l1*256 + l2], l = l1 + 256*l2
//   ZT:    [+131072)            65536 float2, stage-A output: ZT[t1*256 + l1]
constexpr int WS_TERMS = 0;
constexpr int WS_XT    = 8192;
constexpr int WS_ZT    = 8192 + 131072;

// ---------------------------------------------------------------------------
// Kernel 1: per-n setup.  Bc = Vc @ B (complex), terms[n] = {Lambda, a0*b0, a0*b1, a1*b0, a1*b1}
// 512 blocks x 64 threads (1 wave per block); block n computes row-n dot product.
__global__ __launch_bounds__(64) void k_setup(
    const float* __restrict__ Lr, const float* __restrict__ Li,
    const float* __restrict__ pr, const float* __restrict__ pi,
    const float* __restrict__ qr, const float* __restrict__ qi,
    const float* __restrict__ Vr, const float* __restrict__ Vi,
    const float* __restrict__ Ct, const float* __restrict__ Bv,
    float* __restrict__ terms)
{
    int n = blockIdx.x;
    int lane = threadIdx.x;
    float sr = 0.f, si = 0.f;
    #pragma unroll
    for (int m = lane; m < N_; m += 64) {
        float b = Bv[m];
        sr = fmaf(Vr[n * N_ + m], b, sr);
        si = fmaf(Vi[n * N_ + m], b, si);
    }
    #pragma unroll
    for (int off = 32; off > 0; off >>= 1) {
        sr += __shfl_down(sr, off, 64);
        si += __shfl_down(si, off, 64);
    }
    if (lane == 0) {
        float b0r = sr,      b0i = si;           // Bc[n]
        float a0r = Ct[2*n], a0i = -Ct[2*n+1];   // conj(Ct_c)
        float a1r = qr[n],   a1i = -qi[n];       // conj(q)
        float b1r = pr[n],   b1i = pi[n];        // p
        float* t = terms + n * 12;
        t[0]  = Lr[n];                t[1]  = Li[n];
        t[2]  = a0r*b0r - a0i*b0i;    t[3]  = a0r*b0i + a0i*b0r;   // a0*b0
        t[4]  = a0r*b1r - a0i*b1i;    t[5]  = a0r*b1i + a0i*b1r;   // a0*b1
        t[6]  = a1r*b0r - a1i*b0i;    t[7]  = a1r*b0i + a1i*b0r;   // a1*b0
        t[8]  = a1r*b1r - a1i*b1i;    t[9]  = a1r*b1i + a1i*b1r;   // a1*b1
        t[10] = 0.f;                  t[11] = 0.f;
    }
}

// ---------------------------------------------------------------------------
// Kernel 2: the Cauchy reduction + resolvent correction -> atRoots (stored transposed).
// 512 blocks x 256 threads.  Block b covers l in [b*128, b*128+128); two threads per l
// (n-halves 0..255 / 256..511), LDS-combined.  terms reads are wave-uniform -> s_load.
__global__ __launch_bounds__(256) void k_main(
    const float* __restrict__ terms,
    const float* __restrict__ log_step,
    float* __restrict__ XTf)
{
    __shared__ float part[256][9];   // +1 pad: conflict-free lane-strided access
    int tid  = threadIdx.x;
    int lidx = tid & 127;
    int half = tid >> 7;
    int l    = blockIdx.x * 128 + lidx;

    // Per-l quantities in double: Omega = exp(-2*pi*i*l/L), g = (2/step)(1-O)/(1+O), c = 2/(1+O)
    double step  = exp((double)log_step[0]);
    double theta = -6.283185307179586 * ((double)l / 65536.0);
    double sn, cn;
    sincos(theta, &sn, &cn);
    double A  = 1.0 - cn, C = 1.0 + cn, Bm = -sn, D = sn;
    double inv = 1.0 / (C * C + D * D);          // never 0 in double (incl. l = L/2)
    double t2s = 2.0 / step;
    float gr  = (float)(t2s * (A * C + Bm * D) * inv);
    float gi  = (float)(t2s * (Bm * C - A * D) * inv);
    float cr_ = (float)(2.0 * C * inv);
    float ci_ = (float)(-2.0 * D * inv);

    float k0r=0.f,k0i=0.f,k1r=0.f,k1i=0.f,k2r=0.f,k2i=0.f,k3r=0.f,k3i=0.f;
    const float4* t4 = (const float4*)terms + (half * 256) * 3;
    #pragma unroll 8
    for (int n = 0; n < 256; ++n) {
        float4 Aq = t4[n*3 + 0];   // Lr, Li, t0r, t0i
        float4 Bq = t4[n*3 + 1];   // t1r, t1i, t2r, t2i
        float4 Cq = t4[n*3 + 2];   // t3r, t3i, pad, pad
        float dr = gr - Aq.x;
        float di = gi - Aq.y;
        float dd = fmaf(dr, dr, di * di);        // >= 0.01 generically; inf at l=L/2 -> r=0 (safe)
        float iv = __builtin_amdgcn_rcpf(dd);
        float rr = dr * iv;
        float ri = -di * iv;
        k0r = fmaf(rr, Aq.z, k0r); k0r = fmaf(-ri, Aq.w, k0r);
        k0i = fmaf(rr, Aq.w, k0i); k0i = fmaf( ri, Aq.z, k0i);
        k1r = fmaf(rr, Bq.x, k1r); k1r = fmaf(-ri, Bq.y, k1r);
        k1i = fmaf(rr, Bq.y, k1i); k1i = fmaf( ri, Bq.x, k1i);
        k2r = fmaf(rr, Bq.z, k2r); k2r = fmaf(-ri, Bq.w, k2r);
        k2i = fmaf(rr, Bq.w, k2i); k2i = fmaf( ri, Bq.z, k2i);
        k3r = fmaf(rr, Cq.x, k3r); k3r = fmaf(-ri, Cq.y, k3r);
        k3i = fmaf(rr, Cq.y, k3i); k3i = fmaf( ri, Cq.x, k3i);
    }
    part[tid][0]=k0r; part[tid][1]=k0i; part[tid][2]=k1r; part[tid][3]=k1i;
    part[tid][4]=k2r; part[tid][5]=k2i; part[tid][6]=k3r; part[tid][7]=k3i;
    __syncthreads();
    if (tid < 128) {
        float s0r = part[tid][0] + part[tid+128][0];
        float s0i = part[tid][1] + part[tid+128][1];
        float s1r = part[tid][2] + part[tid+128][2];
        float s1i = part[tid][3] + part[tid+128][3];
        float s2r = part[tid][4] + part[tid+128][4];
        float s2i = part[tid][5] + part[tid+128][5];
        float s3r = part[tid][6] + part[tid+128][6];
        float s3i = part[tid][7] + part[tid+128][7];
        // atRoots = c * (k00 - k01*k10/(1+k11))
        float e1r = 1.f + s3r, e1i = s3i;
        float eiv = 1.0f / fmaf(e1r, e1r, e1i * e1i);
        float m_r = s1r * s2r - s1i * s2i;
        float m_i = s1r * s2i + s1i * s2r;
        float q_r = (m_r * e1r + m_i * e1i) * eiv;
        float q_i = (m_i * e1r - m_r * e1i) * eiv;
        float u_r = s0r - q_r;
        float u_i = s0i - q_i;
        float at_r = cr_ * u_r - ci_ * u_i;
        float at_i = cr_ * u_i + ci_ * u_r;
        int l1 = l & 255, l2 = l >> 8;
        ((float2*)XTf)[l1 * 256 + l2] = make_float2(at_r, at_i);
    }
}

// ---------------------------------------------------------------------------
// Kernel 3: FFT stage A.  Block l1: Y[l1,t1] = sum_l2 X[l1+256*l2] * W256^{l2*t1};
// Z = Y * W_L^{l1*t1}; store ZT[t1*256 + l1].  1024 thr = (t1 in [0,256)) x (4-way l2 split).
__global__ __launch_bounds__(1024) void k_fftA(
    const float* __restrict__ XTf, float* __restrict__ ZTf)
{
    __shared__ float2 partA[1024];
    int l1  = blockIdx.x;
    int tid = threadIdx.x;
    int k   = tid & 255;    // t1
    int s   = tid >> 8;     // l2-chunk
    // cur = W256^{64*s*k} in {1,i,-1,-i}; rot = W256^{k}
    int m0 = (s * k) & 3;
    float curR = (m0 == 0) ? 1.f : (m0 == 2 ? -1.f : 0.f);
    float curI = (m0 == 1) ? 1.f : (m0 == 3 ? -1.f : 0.f);
    double rs, rc;
    sincos(6.283185307179586 * ((double)k / 256.0), &rs, &rc);
    float rotR = (float)rc, rotI = (float)rs;
    float yr = 0.f, yi = 0.f;
    const float2* xb = (const float2*)XTf + l1 * 256;
    #pragma unroll 4
    for (int j = s * 64; j < s * 64 + 64; ++j) {
        float2 x = xb[j];   // wave-uniform address -> scalar load
        yr = fmaf(x.x, curR, yr); yr = fmaf(-x.y, curI, yr);
        yi = fmaf(x.x, curI, yi); yi = fmaf( x.y, curR, yi);
        float nR = curR * rotR - curI * rotI;
        float nI = curR * rotI + curI * rotR;
        curR = nR; curI = nI;
    }
    partA[tid] = make_float2(yr, yi);
    __syncthreads();
    if (tid < 256) {
        float2 p0 = partA[tid], p1 = partA[tid+256], p2 = partA[tid+512], p3 = partA[tid+768];
        float Yr = p0.x + p1.x + p2.x + p3.x;
        float Yi = p0.y + p1.y + p2.y + p3.y;
        int mm = (l1 * tid) & 65535;
        double ts, tc;
        sincos(6.283185307179586 * ((double)mm / 65536.0), &ts, &tc);
        float twR = (float)tc, twI = (float)ts;
        ((float2*)ZTf)[tid * 256 + l1] =
            make_float2(Yr * twR - Yi * twI, Yr * twI + Yi * twR);
    }
}

// ---------------------------------------------------------------------------
// Kernel 4: FFT stage B.  Block t1: out[t1+256*t2] = (1/L)*Re( sum_l1 Z[t1,l1]*W256^{l1*t2} ).
__global__ __launch_bounds__(1024) void k_fftB(
    const float* __restrict__ ZTf, float* __restrict__ out)
{
    __shared__ float partB[1024];
    int t1  = blockIdx.x;
    int tid = threadIdx.x;
    int k   = tid & 255;    // t2
    int s   = tid >> 8;
    int m0 = (s * k) & 3;
    float curR = (m0 == 0) ? 1.f : (m0 == 2 ? -1.f : 0.f);
    float curI = (m0 == 1) ? 1.f : (m0 == 3 ? -1.f : 0.f);
    double rs, rc;
    sincos(6.283185307179586 * ((double)k / 256.0), &rs, &rc);
    float rotR = (float)rc, rotI = (float)rs;
    float o = 0.f;
    const float2* zb = (const float2*)ZTf + t1 * 256;
    #pragma unroll 4
    for (int j = s * 64; j < s * 64 + 64; ++j) {
        float2 z = zb[j];   // wave-uniform -> scalar load
        o = fmaf(z.x, curR, o);
        o = fmaf(-z.y, curI, o);
        float nR = curR * rotR - curI * rotI;
        float nI = curR * rotI + curI * rotR;
        curR = nR; curI = nI;
    }
    partB[tid] = o;
    __syncthreads();
    if (tid < 256) {
        float sum = partB[tid] + partB[tid+256] + partB[tid+512] + partB[tid+768];
        out[t1 + 256 * tid] = sum * (1.0f / 65536.0f);
    }
}

// ---------------------------------------------------------------------------
extern "C" void kernel_launch(void* const* d_in, const int* in_sizes, int n_in,
                              void* d_out, int out_size, void* d_ws, size_t ws_size,
                              hipStream_t stream)
{
    const float* Lambda_re = (const float*)d_in[0];
    const float* Lambda_im = (const float*)d_in[1];
    const float* p_re      = (const float*)d_in[2];
    const float* p_im      = (const float*)d_in[3];
    const float* q_re      = (const float*)d_in[4];
    const float* q_im      = (const float*)d_in[5];
    const float* Vc_re     = (const float*)d_in[6];
    const float* Vc_im     = (const float*)d_in[7];
    const float* Ct        = (const float*)d_in[8];
    const float* Bv        = (const float*)d_in[9];
    const float* log_step  = (const float*)d_in[10];

    float* wsf   = (float*)d_ws;
    float* terms = wsf + WS_TERMS;
    float* XT    = wsf + WS_XT;
    float* ZT    = wsf + WS_ZT;
    float* out   = (float*)d_out;

    k_setup<<<512, 64, 0, stream>>>(Lambda_re, Lambda_im, p_re, p_im, q_re, q_im,
                                    Vc_re, Vc_im, Ct, Bv, terms);
    k_main<<<512, 256, 0, stream>>>(terms, log_step, XT);
    k_fftA<<<256, 1024, 0, stream>>>(XT, ZT);
    k_fftB<<<256, 1024, 0, stream>>>(ZT, out);
}

// Round 2
// 140.414 us; speedup vs baseline: 1.1005x; 1.1005x over previous
//
#include <hip/hip_runtime.h>
#include <math.h>

// Problem constants (fixed by setup_inputs)
constexpr int N_ = 512;
constexpr int L_ = 65536;

// ws layout (floats):
//   terms: [0, 8192)            512 * 12 floats: {Lr,Li, t0r,t0i, t1r,t1i, t2r,t2i, t3r,t3i, pad,pad}
//   XT:    [8192, 8192+131072)  65536 float2, transposed atRoots: XT[l1*256 + l2], l = l1 + 256*l2
//   ZT:    [+131072)            65536 float2, stage-A output: ZT[t1*256 + l1]
constexpr int WS_TERMS = 0;
constexpr int WS_XT    = 8192;
constexpr int WS_ZT    = 8192 + 131072;

// ---------------------------------------------------------------------------
// Kernel 1: per-n setup.  Bc = Vc @ B (complex), terms[n] = {Lambda, a0*b0, a0*b1, a1*b0, a1*b1}
__global__ __launch_bounds__(64) void k_setup(
    const float* __restrict__ Lr, const float* __restrict__ Li,
    const float* __restrict__ pr, const float* __restrict__ pi,
    const float* __restrict__ qr, const float* __restrict__ qi,
    const float* __restrict__ Vr, const float* __restrict__ Vi,
    const float* __restrict__ Ct, const float* __restrict__ Bv,
    float* __restrict__ terms)
{
    int n = blockIdx.x;
    int lane = threadIdx.x;
    float sr = 0.f, si = 0.f;
    #pragma unroll
    for (int m = lane; m < N_; m += 64) {
        float b = Bv[m];
        sr = fmaf(Vr[n * N_ + m], b, sr);
        si = fmaf(Vi[n * N_ + m], b, si);
    }
    #pragma unroll
    for (int off = 32; off > 0; off >>= 1) {
        sr += __shfl_down(sr, off, 64);
        si += __shfl_down(si, off, 64);
    }
    if (lane == 0) {
        float b0r = sr,      b0i = si;           // Bc[n]
        float a0r = Ct[2*n], a0i = -Ct[2*n+1];   // conj(Ct_c)
        float a1r = qr[n],   a1i = -qi[n];       // conj(q)
        float b1r = pr[n],   b1i = pi[n];        // p
        float* t = terms + n * 12;
        t[0]  = Lr[n];                t[1]  = Li[n];
        t[2]  = a0r*b0r - a0i*b0i;    t[3]  = a0r*b0i + a0i*b0r;   // a0*b0
        t[4]  = a0r*b1r - a0i*b1i;    t[5]  = a0r*b1i + a0i*b1r;   // a0*b1
        t[6]  = a1r*b0r - a1i*b0i;    t[7]  = a1r*b0i + a1i*b0r;   // a1*b0
        t[8]  = a1r*b1r - a1i*b1i;    t[9]  = a1r*b1i + a1i*b1r;   // a1*b1
        t[10] = 0.f;                  t[11] = 0.f;
    }
}

// ---------------------------------------------------------------------------
// Kernel 2: Cauchy reduction + resolvent correction -> atRoots (stored transposed).
// 1024 blocks x 512 threads = 8192 waves = 32 waves/CU (100% occupancy cap).
// Block covers 64 l values; half = tid>>6 (WAVE-UNIFORM -> terms reads stay scalar)
// selects one of 8 n-chunks of 64.  Two-stage LDS reduction.
__global__ __launch_bounds__(512, 8) void k_main(
    const float* __restrict__ terms,
    const float* __restrict__ log_step,
    float* __restrict__ XTf)
{
    __shared__ float part[8][64][8];   // [half][l][comp]  16 KB; stage-1 reads are 2-way (free)
    __shared__ float red[64][9];       // +1 pad: stage-2 row reads conflict-free (9 coprime 32)
    int tid  = threadIdx.x;
    int lidx = tid & 63;
    int half = tid >> 6;               // wave-uniform
    int l    = blockIdx.x * 64 + lidx;

    // Per-l quantities in double: Omega = exp(-2*pi*i*l/L), g = (2/step)(1-O)/(1+O), c = 2/(1+O)
    double step  = exp((double)log_step[0]);
    double theta = -6.283185307179586 * ((double)l / 65536.0);
    double sn, cn;
    sincos(theta, &sn, &cn);
    double A  = 1.0 - cn, C = 1.0 + cn, Bm = -sn, D = sn;
    double inv = 1.0 / (C * C + D * D);          // never 0 in double (incl. l = L/2)
    double t2s = 2.0 / step;
    float gr  = (float)(t2s * (A * C + Bm * D) * inv);
    float gi  = (float)(t2s * (Bm * C - A * D) * inv);
    float cr_ = (float)(2.0 * C * inv);
    float ci_ = (float)(-2.0 * D * inv);

    float k0r=0.f,k0i=0.f,k1r=0.f,k1i=0.f,k2r=0.f,k2i=0.f,k3r=0.f,k3i=0.f;
    const float4* t4 = (const float4*)terms + (half * 64) * 3;
    #pragma unroll 8
    for (int n = 0; n < 64; ++n) {
        float4 Aq = t4[n*3 + 0];   // Lr, Li, t0r, t0i   (wave-uniform address -> s_load)
        float4 Bq = t4[n*3 + 1];   // t1r, t1i, t2r, t2i
        float4 Cq = t4[n*3 + 2];   // t3r, t3i, pad, pad
        float dr = gr - Aq.x;
        float di = gi - Aq.y;
        float dd = fmaf(dr, dr, di * di);        // inf at l=L/2 -> r=0 (safe, verified r1)
        float iv = __builtin_amdgcn_rcpf(dd);
        float rr = dr * iv;
        float ri = -di * iv;
        k0r = fmaf(rr, Aq.z, k0r); k0r = fmaf(-ri, Aq.w, k0r);
        k0i = fmaf(rr, Aq.w, k0i); k0i = fmaf( ri, Aq.z, k0i);
        k1r = fmaf(rr, Bq.x, k1r); k1r = fmaf(-ri, Bq.y, k1r);
        k1i = fmaf(rr, Bq.y, k1i); k1i = fmaf( ri, Bq.x, k1i);
        k2r = fmaf(rr, Bq.z, k2r); k2r = fmaf(-ri, Bq.w, k2r);
        k2i = fmaf(rr, Bq.w, k2i); k2i = fmaf( ri, Bq.z, k2i);
        k3r = fmaf(rr, Cq.x, k3r); k3r = fmaf(-ri, Cq.y, k3r);
        k3i = fmaf(rr, Cq.y, k3i); k3i = fmaf( ri, Cq.x, k3i);
    }
    part[half][lidx][0]=k0r; part[half][lidx][1]=k0i;
    part[half][lidx][2]=k1r; part[half][lidx][3]=k1i;
    part[half][lidx][4]=k2r; part[half][lidx][5]=k2i;
    part[half][lidx][6]=k3r; part[half][lidx][7]=k3i;
    __syncthreads();
    // Stage 1: 512 threads, one per (l, comp) slot; sum 8 halves.
    {
        int lr2 = tid >> 3, c = tid & 7;
        float s = 0.f;
        #pragma unroll
        for (int h = 0; h < 8; ++h) s += part[h][lr2][c];
        red[lr2][c] = s;
    }
    __syncthreads();
    // Stage 2: thread tid<64 owns l = blk*64+tid (its own gr/cr_ match: lidx==tid).
    if (tid < 64) {
        float s0r = red[tid][0], s0i = red[tid][1];
        float s1r = red[tid][2], s1i = red[tid][3];
        float s2r = red[tid][4], s2i = red[tid][5];
        float s3r = red[tid][6], s3i = red[tid][7];
        // atRoots = c * (k00 - k01*k10/(1+k11))
        float e1r = 1.f + s3r, e1i = s3i;
        float eiv = 1.0f / fmaf(e1r, e1r, e1i * e1i);
        float m_r = s1r * s2r - s1i * s2i;
        float m_i = s1r * s2i + s1i * s2r;
        float q_r = (m_r * e1r + m_i * e1i) * eiv;
        float q_i = (m_i * e1r - m_r * e1i) * eiv;
        float u_r = s0r - q_r;
        float u_i = s0i - q_i;
        float at_r = cr_ * u_r - ci_ * u_i;
        float at_i = cr_ * u_i + ci_ * u_r;
        int l1 = l & 255, l2 = l >> 8;
        ((float2*)XTf)[l1 * 256 + l2] = make_float2(at_r, at_i);
    }
}

// ---------------------------------------------------------------------------
// Kernel 3: FFT stage A.  Block l1: Y[l1,t1] = sum_l2 X[l1+256*l2] * W256^{l2*t1};
// Z = Y * W_L^{l1*t1}; store ZT[t1*256 + l1].  Input row staged in LDS (broadcast reads).
__global__ __launch_bounds__(1024) void k_fftA(
    const float* __restrict__ XTf, float* __restrict__ ZTf)
{
    __shared__ float2 xrow[256];
    __shared__ float2 partA[1024];
    int l1  = blockIdx.x;
    int tid = threadIdx.x;
    if (tid < 256) xrow[tid] = ((const float2*)XTf)[l1 * 256 + tid];
    int k   = tid & 255;    // t1
    int s   = tid >> 8;     // l2-chunk
    // cur = W256^{64*s*k} in {1,i,-1,-i}; rot = W256^{k} (double-seeded: recurrence-critical)
    int m0 = (s * k) & 3;
    float curR = (m0 == 0) ? 1.f : (m0 == 2 ? -1.f : 0.f);
    float curI = (m0 == 1) ? 1.f : (m0 == 3 ? -1.f : 0.f);
    double rs, rc;
    sincos(6.283185307179586 * ((double)k / 256.0), &rs, &rc);
    float rotR = (float)rc, rotI = (float)rs;
    __syncthreads();
    float yr = 0.f, yi = 0.f;
    #pragma unroll 8
    for (int j = s * 64; j < s * 64 + 64; ++j) {
        float2 x = xrow[j];   // wave-uniform -> LDS broadcast, conflict-free
        yr = fmaf(x.x, curR, yr); yr = fmaf(-x.y, curI, yr);
        yi = fmaf(x.x, curI, yi); yi = fmaf( x.y, curR, yi);
        float nR = curR * rotR - curI * rotI;
        float nI = curR * rotI + curI * rotR;
        curR = nR; curI = nI;
    }
    partA[tid] = make_float2(yr, yi);
    __syncthreads();
    if (tid < 256) {
        float2 p0 = partA[tid], p1 = partA[tid+256], p2 = partA[tid+512], p3 = partA[tid+768];
        float Yr = p0.x + p1.x + p2.x + p3.x;
        float Yi = p0.y + p1.y + p2.y + p3.y;
        int mm = (l1 * tid) & 65535;
        float tv = (float)mm * (1.0f / 65536.0f);   // exact in fp32 (mm < 2^16)
        float twR = __builtin_amdgcn_cosf(tv);      // v_cos_f32: cos(2*pi*tv)
        float twI = __builtin_amdgcn_sinf(tv);      // v_sin_f32: sin(2*pi*tv)
        ((float2*)ZTf)[tid * 256 + l1] =
            make_float2(Yr * twR - Yi * twI, Yr * twI + Yi * twR);
    }
}

// ---------------------------------------------------------------------------
// Kernel 4: FFT stage B.  Block t1: out[t1+256*t2] = (1/L)*Re( sum_l1 Z[t1,l1]*W256^{l1*t2} ).
__global__ __launch_bounds__(1024) void k_fftB(
    const float* __restrict__ ZTf, float* __restrict__ out)
{
    __shared__ float2 zrow[256];
    __shared__ float partB[1024];
    int t1  = blockIdx.x;
    int tid = threadIdx.x;
    if (tid < 256) zrow[tid] = ((const float2*)ZTf)[t1 * 256 + tid];
    int k   = tid & 255;    // t2
    int s   = tid >> 8;
    int m0 = (s * k) & 3;
    float curR = (m0 == 0) ? 1.f : (m0 == 2 ? -1.f : 0.f);
    float curI = (m0 == 1) ? 1.f : (m0 == 3 ? -1.f : 0.f);
    double rs, rc;
    sincos(6.283185307179586 * ((double)k / 256.0), &rs, &rc);
    float rotR = (float)rc, rotI = (float)rs;
    __syncthreads();
    float o = 0.f;
    #pragma unroll 8
    for (int j = s * 64; j < s * 64 + 64; ++j) {
        float2 z = zrow[j];   // LDS broadcast
        o = fmaf(z.x, curR, o);
        o = fmaf(-z.y, curI, o);
        float nR = curR * rotR - curI * rotI;
        float nI = curR * rotI + curI * rotR;
        curR = nR; curI = nI;
    }
    partB[tid] = o;
    __syncthreads();
    if (tid < 256) {
        float sum = partB[tid] + partB[tid+256] + partB[tid+512] + partB[tid+768];
        out[t1 + 256 * tid] = sum * (1.0f / 65536.0f);
    }
}

// ---------------------------------------------------------------------------
extern "C" void kernel_launch(void* const* d_in, const int* in_sizes, int n_in,
                              void* d_out, int out_size, void* d_ws, size_t ws_size,
                              hipStream_t stream)
{
    const float* Lambda_re = (const float*)d_in[0];
    const float* Lambda_im = (const float*)d_in[1];
    const float* p_re      = (const float*)d_in[2];
    const float* p_im      = (const float*)d_in[3];
    const float* q_re      = (const float*)d_in[4];
    const float* q_im      = (const float*)d_in[5];
    const float* Vc_re     = (const float*)d_in[6];
    const float* Vc_im     = (const float*)d_in[7];
    const float* Ct        = (const float*)d_in[8];
    const float* Bv        = (const float*)d_in[9];
    const float* log_step  = (const float*)d_in[10];

    float* wsf   = (float*)d_ws;
    float* terms = wsf + WS_TERMS;
    float* XT    = wsf + WS_XT;
    float* ZT    = wsf + WS_ZT;
    float* out   = (float*)d_out;

    k_setup<<<512, 64, 0, stream>>>(Lambda_re, Lambda_im, p_re, p_im, q_re, q_im,
                                    Vc_re, Vc_im, Ct, Bv, terms);
    k_main<<<1024, 512, 0, stream>>>(terms, log_step, XT);
    k_fftA<<<256, 1024, 0, stream>>>(XT, ZT);
    k_fftB<<<256, 1024, 0, stream>>>(ZT, out);
}

// Round 3
// 107.327 us; speedup vs baseline: 1.4398x; 1.3083x over previous
//
#include <hip/hip_runtime.h>
#include <math.h>

// ws layout (floats):
//   terms: [0, 6144)        512 * 12 floats {Lr,Li, t0r,t0i, t1r,t1i, t2r,t2i, t3r,t3i, pad,pad}
//   ZT:    [8192, +131072)  65536 float2, stage-A output: ZT[t1*256 + l1]
constexpr int WS_TERMS = 0;
constexpr int WS_ZT    = 8192;

// ---------------------------------------------------------------------------
// Kernel 1: per-n setup.  Bc = Vc @ B (complex), terms[n] = {Lambda, a0*b0, a0*b1, a1*b0, a1*b1}
// 512 blocks x 256 threads; block n does the row-n dot product (4 waves, shfl+LDS reduce).
__global__ __launch_bounds__(256) void k_setup(
    const float* __restrict__ Lr, const float* __restrict__ Li,
    const float* __restrict__ pr, const float* __restrict__ pi,
    const float* __restrict__ qr, const float* __restrict__ qi,
    const float* __restrict__ Vr, const float* __restrict__ Vi,
    const float* __restrict__ Ct, const float* __restrict__ Bv,
    float* __restrict__ terms)
{
    __shared__ float red[8];
    int n = blockIdx.x;
    int t = threadIdx.x;
    float b0 = Bv[t], b1 = Bv[t + 256];
    float sr = fmaf(Vr[n*512 + t], b0, Vr[n*512 + t + 256] * b1);
    float si = fmaf(Vi[n*512 + t], b0, Vi[n*512 + t + 256] * b1);
    #pragma unroll
    for (int off = 32; off > 0; off >>= 1) {
        sr += __shfl_down(sr, off, 64);
        si += __shfl_down(si, off, 64);
    }
    if ((t & 63) == 0) { red[(t >> 6)*2] = sr; red[(t >> 6)*2 + 1] = si; }
    __syncthreads();
    if (t == 0) {
        float b0r = red[0] + red[2] + red[4] + red[6];
        float b0i = red[1] + red[3] + red[5] + red[7];
        float a0r = Ct[2*n], a0i = -Ct[2*n+1];   // conj(Ct_c)
        float a1r = qr[n],   a1i = -qi[n];       // conj(q)
        float b1r = pr[n],   b1i = pi[n];        // p
        float* tm = terms + n * 12;
        tm[0]  = Lr[n];                tm[1]  = Li[n];
        tm[2]  = a0r*b0r - a0i*b0i;    tm[3]  = a0r*b0i + a0i*b0r;
        tm[4]  = a0r*b1r - a0i*b1i;    tm[5]  = a0r*b1i + a0i*b1r;
        tm[6]  = a1r*b0r - a1i*b0i;    tm[7]  = a1r*b0i + a1i*b0r;
        tm[8]  = a1r*b1r - a1i*b1i;    tm[9]  = a1r*b1i + a1i*b1r;
        tm[10] = 0.f;                  tm[11] = 0.f;
    }
}

// ---------------------------------------------------------------------------
// Kernel 2 (fused): Cauchy reduction + resolvent + FFT stage A.
// Grid 256 blocks x 1024 threads; block = l1 owns all l = l1 + 256*l2, l2 in [0,256).
// Thread (u = tid&127, chunk = tid>>7): l2 in {u, u+128}, n in [chunk*64, chunk*64+64).
// terms staged in LDS; inner reads are wave-uniform ds_read_b128 broadcasts.
// LDS overlay (floats):
//   phase 1-2: terms[6144] @0
//   phase 3-4: part[4][256][9] @0 (9-pad: conflict-free), red[256][9] @9216
//   phase 5-6: xrow float2[256] @0, partA float2[1024] @512  (red still @9216)
__global__ __launch_bounds__(1024, 8) void k_mainA(
    const float* __restrict__ terms,
    const float* __restrict__ log_step,
    float* __restrict__ ZTf)
{
    __shared__ float buf[11520];   // 45 KB
    int tid = threadIdx.x;
    int l1  = blockIdx.x;

    // ---- stage terms -> LDS (1536 float4, coalesced)
    {
        float4* dst = (float4*)buf;
        const float4* src = (const float4*)terms;
        for (int i = tid; i < 1536; i += 1024) dst[i] = src[i];
    }

    int u     = tid & 127;
    int chunk = tid >> 7;          // wave-uniform (changes every 2 waves)

    // ---- per-l params for l = l1+256*u (h=0) and l+32768 (h=1), double precision.
    // h=1 via theta-pi keeps the l=L/2 numerics identical to validated rounds 1-2.
    double step = exp((double)log_step[0]);
    double t2s  = 2.0 / step;
    double th0  = -6.283185307179586 * ((double)(l1 + 256*u) / 65536.0);
    float gr[2], gi[2], cr_[2], ci_[2];
    #pragma unroll
    for (int h = 0; h < 2; ++h) {
        double th = th0 - 3.141592653589793 * (double)h;
        double sn, cn; sincos(th, &sn, &cn);
        double A = 1.0 - cn, C = 1.0 + cn, Bm = -sn, D = sn;
        double inv = 1.0 / (C*C + D*D);
        gr[h]  = (float)(t2s * (A*C + Bm*D) * inv);
        gi[h]  = (float)(t2s * (Bm*C - A*D) * inv);
        cr_[h] = (float)(2.0 * C * inv);
        ci_[h] = (float)(-2.0 * D * inv);
    }
    __syncthreads();

    // ---- Cauchy loop: 64 n from LDS, 2 l's per read triple
    float ac[2][8];
    #pragma unroll
    for (int h = 0; h < 2; ++h)
        #pragma unroll
        for (int c = 0; c < 8; ++c) ac[h][c] = 0.f;

    const float4* t4 = (const float4*)buf + chunk * 64 * 3;
    #pragma unroll 2
    for (int n = 0; n < 64; ++n) {
        float4 Aq = t4[n*3 + 0];   // Lr, Li, t0r, t0i  (broadcast ds_read_b128)
        float4 Bq = t4[n*3 + 1];   // t1r, t1i, t2r, t2i
        float4 Cq = t4[n*3 + 2];   // t3r, t3i, -, -
        #pragma unroll
        for (int h = 0; h < 2; ++h) {
            float dr = gr[h] - Aq.x;
            float di = gi[h] - Aq.y;
            float dd = fmaf(dr, dr, di * di);    // inf at l=L/2 -> r=0 (validated)
            float iv = __builtin_amdgcn_rcpf(dd);
            float rr = dr * iv;
            float ri = -di * iv;
            ac[h][0] = fmaf(rr, Aq.z, ac[h][0]); ac[h][0] = fmaf(-ri, Aq.w, ac[h][0]);
            ac[h][1] = fmaf(rr, Aq.w, ac[h][1]); ac[h][1] = fmaf( ri, Aq.z, ac[h][1]);
            ac[h][2] = fmaf(rr, Bq.x, ac[h][2]); ac[h][2] = fmaf(-ri, Bq.y, ac[h][2]);
            ac[h][3] = fmaf(rr, Bq.y, ac[h][3]); ac[h][3] = fmaf( ri, Bq.x, ac[h][3]);
            ac[h][4] = fmaf(rr, Bq.z, ac[h][4]); ac[h][4] = fmaf(-ri, Bq.w, ac[h][4]);
            ac[h][5] = fmaf(rr, Bq.w, ac[h][5]); ac[h][5] = fmaf( ri, Bq.z, ac[h][5]);
            ac[h][6] = fmaf(rr, Cq.x, ac[h][6]); ac[h][6] = fmaf(-ri, Cq.y, ac[h][6]);
            ac[h][7] = fmaf(rr, Cq.y, ac[h][7]); ac[h][7] = fmaf( ri, Cq.x, ac[h][7]);
        }
    }
    __syncthreads();   // all terms reads done; LDS is reusable

    // ---- partials: chunks 4..7 write part[chunk-4][l2][c], then 0..3 accumulate
    if (chunk >= 4) {
        #pragma unroll
        for (int h = 0; h < 2; ++h) {
            float* p = buf + (chunk - 4) * 2304 + (u + 128*h) * 9;
            #pragma unroll
            for (int c = 0; c < 8; ++c) p[c] = ac[h][c];
        }
    }
    __syncthreads();
    if (chunk < 4) {
        #pragma unroll
        for (int h = 0; h < 2; ++h) {
            float* p = buf + chunk * 2304 + (u + 128*h) * 9;
            #pragma unroll
            for (int c = 0; c < 8; ++c) p[c] += ac[h][c];
        }
    }
    __syncthreads();

    // ---- stage-1 reduce: 2048 slots (l2*8+c), sum over 4 part-planes -> red
    for (int s = tid; s < 2048; s += 1024) {
        int a = (s >> 3) * 9 + (s & 7);
        float v = buf[a] + buf[2304 + a] + buf[4608 + a] + buf[6912 + a];
        buf[9216 + a] = v;
    }
    __syncthreads();

    // ---- stage-2: atRoots for l2 = tid (tid<256); own params: h = tid>>7
    if (tid < 256) {
        const float* rd = buf + 9216 + tid * 9;
        float s0r = rd[0], s0i = rd[1], s1r = rd[2], s1i = rd[3];
        float s2r = rd[4], s2i = rd[5], s3r = rd[6], s3i = rd[7];
        int h = tid >> 7;
        float e1r = 1.f + s3r, e1i = s3i;
        float eiv = 1.0f / fmaf(e1r, e1r, e1i * e1i);
        float m_r = s1r * s2r - s1i * s2i;
        float m_i = s1r * s2i + s1i * s2r;
        float q_r = (m_r * e1r + m_i * e1i) * eiv;
        float q_i = (m_i * e1r - m_r * e1i) * eiv;
        float u_r = s0r - q_r;
        float u_i = s0i - q_i;
        float at_r = cr_[h] * u_r - ci_[h] * u_i;
        float at_i = cr_[h] * u_i + ci_[h] * u_r;
        ((float2*)buf)[tid] = make_float2(at_r, at_i);   // xrow @0 (part[0..128] dead)
    }
    __syncthreads();

    // ---- FFT stage A over l2 (256-pt DFT, 4-way split) + W_L twiddle -> ZT
    {
        int k = tid & 255;    // t1
        int s = tid >> 8;     // l2-chunk
        int m0 = (s * k) & 3;
        float curR = (m0 == 0) ? 1.f : (m0 == 2 ? -1.f : 0.f);
        float curI = (m0 == 1) ? 1.f : (m0 == 3 ? -1.f : 0.f);
        double rs, rc;
        sincos(6.283185307179586 * ((double)k / 256.0), &rs, &rc);
        float rotR = (float)rc, rotI = (float)rs;
        const float2* xrow = (const float2*)buf;
        float yr = 0.f, yi = 0.f;
        #pragma unroll 8
        for (int j = s * 64; j < s * 64 + 64; ++j) {
            float2 x = xrow[j];   // broadcast
            yr = fmaf(x.x, curR, yr); yr = fmaf(-x.y, curI, yr);
            yi = fmaf(x.x, curI, yi); yi = fmaf( x.y, curR, yi);
            float nR = curR * rotR - curI * rotI;
            float nI = curR * rotI + curI * rotR;
            curR = nR; curI = nI;
        }
        ((float2*)(buf + 512))[tid] = make_float2(yr, yi);   // partA @512
    }
    __syncthreads();
    if (tid < 256) {
        const float2* pA = (const float2*)(buf + 512);
        float2 p0 = pA[tid], p1 = pA[tid+256], p2 = pA[tid+512], p3 = pA[tid+768];
        float Yr = p0.x + p1.x + p2.x + p3.x;
        float Yi = p0.y + p1.y + p2.y + p3.y;
        int mm = (l1 * tid) & 65535;
        float tv = (float)mm * (1.0f / 65536.0f);   // exact in fp32
        float twR = __builtin_amdgcn_cosf(tv);
        float twI = __builtin_amdgcn_sinf(tv);
        ((float2*)ZTf)[tid * 256 + l1] =
            make_float2(Yr * twR - Yi * twI, Yr * twI + Yi * twR);
    }
}

// ---------------------------------------------------------------------------
// Kernel 3: FFT stage B.  Block t1: out[t1+256*t2] = (1/L)*Re( sum_l1 Z[t1,l1]*W256^{l1*t2} ).
__global__ __launch_bounds__(1024) void k_fftB(
    const float* __restrict__ ZTf, float* __restrict__ out)
{
    __shared__ float2 zrow[256];
    __shared__ float partB[1024];
    int t1  = blockIdx.x;
    int tid = threadIdx.x;
    if (tid < 256) zrow[tid] = ((const float2*)ZTf)[t1 * 256 + tid];
    int k   = tid & 255;    // t2
    int s   = tid >> 8;
    int m0 = (s * k) & 3;
    float curR = (m0 == 0) ? 1.f : (m0 == 2 ? -1.f : 0.f);
    float curI = (m0 == 1) ? 1.f : (m0 == 3 ? -1.f : 0.f);
    double rs, rc;
    sincos(6.283185307179586 * ((double)k / 256.0), &rs, &rc);
    float rotR = (float)rc, rotI = (float)rs;
    __syncthreads();
    float o = 0.f;
    #pragma unroll 8
    for (int j = s * 64; j < s * 64 + 64; ++j) {
        float2 z = zrow[j];   // broadcast
        o = fmaf(z.x, curR, o);
        o = fmaf(-z.y, curI, o);
        float nR = curR * rotR - curI * rotI;
        float nI = curR * rotI + curI * rotR;
        curR = nR; curI = nI;
    }
    partB[tid] = o;
    __syncthreads();
    if (tid < 256) {
        float sum = partB[tid] + partB[tid+256] + partB[tid+512] + partB[tid+768];
        out[t1 + 256 * tid] = sum * (1.0f / 65536.0f);
    }
}

// ---------------------------------------------------------------------------
extern "C" void kernel_launch(void* const* d_in, const int* in_sizes, int n_in,
                              void* d_out, int out_size, void* d_ws, size_t ws_size,
                              hipStream_t stream)
{
    const float* Lambda_re = (const float*)d_in[0];
    const float* Lambda_im = (const float*)d_in[1];
    const float* p_re      = (const float*)d_in[2];
    const float* p_im      = (const float*)d_in[3];
    const float* q_re      = (const float*)d_in[4];
    const float* q_im      = (const float*)d_in[5];
    const float* Vc_re     = (const float*)d_in[6];
    const float* Vc_im     = (const float*)d_in[7];
    const float* Ct        = (const float*)d_in[8];
    const float* Bv        = (const float*)d_in[9];
    const float* log_step  = (const float*)d_in[10];

    float* wsf   = (float*)d_ws;
    float* terms = wsf + WS_TERMS;
    float* ZT    = wsf + WS_ZT;
    float* out   = (float*)d_out;

    k_setup<<<512, 256, 0, stream>>>(Lambda_re, Lambda_im, p_re, p_im, q_re, q_im,
                                     Vc_re, Vc_im, Ct, Bv, terms);
    k_mainA<<<256, 1024, 0, stream>>>(terms, log_step, ZT);
    k_fftB<<<256, 1024, 0, stream>>>(ZT, out);
}